// Round 8
// baseline (30.698 us; speedup 1.0000x reference)
//
#include <hip/hip_runtime.h>
#include <hip/hip_bf16.h>

// out[b,i,p] = sum_{j!=i} relu( U[b,i,p] + V[b,j,p] + c[p] )
//   Wf[q][d] = sum_o W2[q&255][o] * W1[o][(q>=256)*512+d]
//   U/V[i][p] = sum_d x[i][d] * Wf[p or 256+p][d],  c = W2@b1 + b2
// SINGLE kernel, 256 blocks x 512 thr, zero inter-block communication:
// each block (b,pc) recomputes its own 64 Wf rows from W1/W2 chunk-by-chunk
// (chained GEMM in LDS), then does the main GEMM + pairwise epilogue.
// No workspace, no memset, no flags (R5/R7 lesson: those cost more than a launch).

typedef unsigned short u16;
typedef __attribute__((ext_vector_type(8))) short short8v;
typedef __attribute__((ext_vector_type(4))) short short4v;
typedef __attribute__((ext_vector_type(4))) float float4v;
typedef __attribute__((ext_vector_type(2))) float float2v;

__device__ __forceinline__ u16 f2bf(float f) {
    unsigned u = __float_as_uint(f);
    return (u16)((u + 0x7fffu + ((u >> 16) & 1u)) >> 16);
}

__device__ __forceinline__ short8v cvt8v(float4v a, float4v b) {
    union { u16 us[8]; short8v v; } o;
    o.us[0] = f2bf(a.x); o.us[1] = f2bf(a.y); o.us[2] = f2bf(a.z); o.us[3] = f2bf(a.w);
    o.us[4] = f2bf(b.x); o.us[5] = f2bf(b.y); o.us[6] = f2bf(b.z); o.us[7] = f2bf(b.w);
    return o.v;
}

// LDS map (bytes):
//   Xs    [64][520] u16   66560 @ 0        (epilogue reuses as Us/Vs [64][34] f32)
//   W1ts  2x[64][264] u16 67584 @ 66560    (double-buffered W1^T chunks)
//   W2s   [32][264] u16   16896 @ 134144
//   Wfs   2x[32][144 B]    9216 @ 151040   (double-buffered Wf chunk, bf16 [p][d])
//   cvc   [32] f32 + pad    256 @ 160256
#define XS_OFF   0
#define W1_OFF   66560
#define W1_BUF   33792
#define W2_OFF   134144
#define WFS_OFF  151040
#define WFS_BUF  4608
#define CVC_OFF  160256
#define LDS_TOTAL 160512

__global__ __launch_bounds__(512, 1) void solo_kernel(
    const float* __restrict__ x, const float* __restrict__ W1,
    const float* __restrict__ b1, const float* __restrict__ W2,
    const float* __restrict__ b2, float* __restrict__ out) {
    __shared__ __align__(16) unsigned char smem[LDS_TOTAL];
    u16* Xs    = (u16*)(smem + XS_OFF);
    u16* W1ts0 = (u16*)(smem + W1_OFF);
    u16* W1ts1 = (u16*)(smem + W1_OFF + W1_BUF);
    u16* W2s   = (u16*)(smem + W2_OFF);
    unsigned char* Wfs0 = smem + WFS_OFF;
    unsigned char* Wfs1 = smem + WFS_OFF + WFS_BUF;
    float* cvc = (float*)(smem + CVC_OFF);

    const int bid = blockIdx.x, tid = threadIdx.x;
    const int lane = tid & 63, w = tid >> 6;          // 8 waves
    const int b = ((bid & 7) << 2) | ((bid >> 3) & 3);  // 4 b-panels per XCD
    const int pc = bid >> 5, p0 = pc * 32;
    const int rQ = lane >> 4, rM = lane & 15;
    const int dt = w >> 1, pt = w & 1;   // wave tile: rows dt*16 (d or i), cols pt*16 (p)

    // ---- prologue: stage Xs (x fp32->bf16), W2s, cvec, W1t chunk 0 ----
#pragma unroll
    for (int rr = 0; rr < 8; ++rr) {
        int row = w * 8 + rr;
        const float* s = x + (b * 64 + row) * 512 + lane * 8;
        float4v a0 = *(const float4v*)s, a1 = *(const float4v*)(s + 4);
        *(short8v*)&Xs[row * 520 + lane * 8] = cvt8v(a0, a1);
    }
#pragma unroll
    for (int rr = 0; rr < 2; ++rr) {
        int row = w * 4 + rr * 2 + (lane >> 5);       // 0..31
        int c = lane & 31;
        const float* s = W2 + (p0 + row) * 256 + c * 8;
        float4v a0 = *(const float4v*)s, a1 = *(const float4v*)(s + 4);
        *(short8v*)&W2s[row * 264 + c * 8] = cvt8v(a0, a1);
    }
    if (w == 0 && lane < 32) {
        float acc = b2[p0 + lane];
        const float4v* wr = (const float4v*)(W2 + (p0 + lane) * 256);
#pragma unroll 8
        for (int o4 = 0; o4 < 64; ++o4) {
            float4v wv = wr[o4];
            float4v bv = *(const float4v*)(b1 + o4 * 4);
            acc += wv.x * bv.x + wv.y * bv.y + wv.z * bv.z + wv.w * bv.w;
        }
        cvc[lane] = acc;
    }

    // W1^T chunk staging (split: load-early / write-late), 4x4 reg transpose.
    const int d4s = (tid & 15) * 4;
    const int ogs = tid >> 4;                          // 0..31
    float4v sf[2][4];
    auto stage_load = [&](int ch) {
#pragma unroll
        for (int kk = 0; kk < 2; ++kk) {
            const int o0 = kk * 128 + ogs * 4;
            const float* s0 = W1 + o0 * 1024 + ((ch >> 3) * 512 + (ch & 7) * 64) + d4s;
#pragma unroll
            for (int j = 0; j < 4; ++j)
                sf[kk][j] = *(const float4v*)(s0 + j * 1024);
        }
    };
    auto stage_write = [&](u16* dst) {
#pragma unroll
        for (int kk = 0; kk < 2; ++kk) {
            const int o0 = kk * 128 + ogs * 4;
            const int u = o0 >> 3, sub = o0 & 7;
#pragma unroll
            for (int dd = 0; dd < 4; ++dd) {
                int d = d4s + dd;
                int usw = u ^ ((d >> 3) & 7);
                union { u16 us[4]; short4v v; } pk;
                pk.us[0] = f2bf(sf[0][dd].x); // note: sf[kk][j][dd] -> element dd of row j
                pk.us[0] = f2bf(sf[kk][0][dd]);
                pk.us[1] = f2bf(sf[kk][1][dd]);
                pk.us[2] = f2bf(sf[kk][2][dd]);
                pk.us[3] = f2bf(sf[kk][3][dd]);
                *(short4v*)&dst[d * 264 + usw * 8 + sub] = pk.v;
            }
        }
    };

    stage_load(0);
    stage_write(W1ts0);
    __syncthreads();

    // ---- chunk loop: 16 chunks (8 U + 8 V), 1 barrier each ----
    float4v Uacc = {0.f, 0.f, 0.f, 0.f}, Vacc = {0.f, 0.f, 0.f, 0.f};
    const int arow = dt * 16 + rM;                     // W1t local d-row
    const int axor = (arow >> 3) & 7;
    const int brow = pt * 16 + rM;                     // W2s / Wfs p-row

    for (int cc = 0; cc < 16; ++cc) {
        u16* cur = (cc & 1) ? W1ts1 : W1ts0;
        u16* nxt = (cc & 1) ? W1ts0 : W1ts1;
        unsigned char* wfcur  = (cc & 1) ? Wfs1 : Wfs0;
        unsigned char* wfprev = (cc & 1) ? Wfs0 : Wfs1;

        if (cc < 15) stage_load(cc + 1);               // issue early (T14)

        // Wf-GEMM: D[d][p] tile (16x16), K=256
        float4v wf = {0.f, 0.f, 0.f, 0.f};
#pragma unroll
        for (int ks = 0; ks < 8; ++ks) {
            short8v a  = *(const short8v*)&cur[arow * 264 + ((ks * 4 + rQ) ^ axor) * 8];
            short8v bq = *(const short8v*)&W2s[brow * 264 + (ks * 4 + rQ) * 8];
            wf = __builtin_amdgcn_mfma_f32_16x16x32_bf16(a, bq, wf, 0, 0, 0);
        }
        {   // store transposed: Wfs[p][d], 4 consecutive d per lane -> one b64 write
            union { u16 us[4]; short4v v; } pk;
            pk.us[0] = f2bf(wf[0]); pk.us[1] = f2bf(wf[1]);
            pk.us[2] = f2bf(wf[2]); pk.us[3] = f2bf(wf[3]);
            *(short4v*)(wfcur + brow * 144 + (dt * 16 + rQ * 4) * 2) = pk.v;
        }

        // main-GEMM: consume chunk cc-1 (from Wfs written last iter)
        if (cc > 0) {
            const int k = cc - 1, c = k & 7;
            if (k < 8) {
#pragma unroll
                for (int ks2 = 0; ks2 < 2; ++ks2) {
                    short8v a  = *(const short8v*)&Xs[arow * 520 + (c * 8 + ks2 * 4 + rQ) * 8];
                    short8v bq = *(const short8v*)(wfprev + brow * 144 + (ks2 * 4 + rQ) * 16);
                    Uacc = __builtin_amdgcn_mfma_f32_16x16x32_bf16(a, bq, Uacc, 0, 0, 0);
                }
            } else {
#pragma unroll
                for (int ks2 = 0; ks2 < 2; ++ks2) {
                    short8v a  = *(const short8v*)&Xs[arow * 520 + (c * 8 + ks2 * 4 + rQ) * 8];
                    short8v bq = *(const short8v*)(wfprev + brow * 144 + (ks2 * 4 + rQ) * 16);
                    Vacc = __builtin_amdgcn_mfma_f32_16x16x32_bf16(a, bq, Vacc, 0, 0, 0);
                }
            }
        }

        if (cc < 15) stage_write(nxt);                 // write late (after loads land)
        __syncthreads();
    }

    // final main-GEMM: chunk 15 (V phase, c=7) from Wfs1
#pragma unroll
    for (int ks2 = 0; ks2 < 2; ++ks2) {
        short8v a  = *(const short8v*)&Xs[arow * 520 + (7 * 8 + ks2 * 4 + rQ) * 8];
        short8v bq = *(const short8v*)(Wfs1 + brow * 144 + (ks2 * 4 + rQ) * 16);
        Vacc = __builtin_amdgcn_mfma_f32_16x16x32_bf16(a, bq, Vacc, 0, 0, 0);
    }
    __syncthreads();   // all Xs reads done; reuse for Us/Vs [64][34] f32

    float* Us = (float*)smem;
    float* Vs = Us + 64 * 34;
#pragma unroll
    for (int r = 0; r < 4; ++r) {
        Us[(dt * 16 + rQ * 4 + r) * 34 + pt * 16 + rM] = Uacc[r];
        Vs[(dt * 16 + rQ * 4 + r) * 34 + pt * 16 + rM] = Vacc[r];
    }
    __syncthreads();

    // pairwise epilogue: p2 = tid&15 (2 p via float2), ig = tid>>4 (2 i-rows)
    const int p2 = tid & 15;
    const int ig = tid >> 4;    // 0..31
    float2v cv = *(const float2v*)&cvc[p2 * 2];
    float2v u2[2], acc2[2];
#pragma unroll
    for (int ii = 0; ii < 2; ++ii) {
        float2v uu = *(const float2v*)&Us[(ig * 2 + ii) * 34 + p2 * 2];
        u2[ii].x = uu.x + cv.x; u2[ii].y = uu.y + cv.y;
        acc2[ii].x = 0.f; acc2[ii].y = 0.f;
    }
#pragma unroll 8
    for (int j = 0; j < 64; ++j) {
        float2v v = *(const float2v*)&Vs[j * 34 + p2 * 2];
#pragma unroll
        for (int ii = 0; ii < 2; ++ii) {
            acc2[ii].x += fmaxf(u2[ii].x + v.x, 0.f);
            acc2[ii].y += fmaxf(u2[ii].y + v.y, 0.f);
        }
    }
#pragma unroll
    for (int ii = 0; ii < 2; ++ii) {
        int i = ig * 2 + ii;
        float2v vd = *(const float2v*)&Vs[i * 34 + p2 * 2];
        acc2[ii].x -= fmaxf(u2[ii].x + vd.x, 0.f);
        acc2[ii].y -= fmaxf(u2[ii].y + vd.y, 0.f);
        *(float2v*)&out[(b * 64 + i) * 256 + p0 + p2 * 2] = acc2[ii];
    }
}

// ---------------------------------------------------------------------------
extern "C" void kernel_launch(void* const* d_in, const int* in_sizes, int n_in,
                              void* d_out, int out_size, void* d_ws, size_t ws_size,
                              hipStream_t stream) {
    const float* x  = (const float*)d_in[0];   // (32,64,512)
    const float* W1 = (const float*)d_in[1];   // (256,1024)
    const float* b1 = (const float*)d_in[2];   // (256,)
    const float* W2 = (const float*)d_in[3];   // (256,256)
    const float* b2 = (const float*)d_in[4];   // (256,)
    float* out = (float*)d_out;                // (32,64,256)

    solo_kernel<<<256, 512, 0, stream>>>(x, W1, b1, W2, b2, out);
}

// Round 9
// 21.175 us; speedup vs baseline: 1.4497x; 1.4497x over previous
//
#include <hip/hip_runtime.h>
#include <hip/hip_bf16.h>

// out[b,i,p] = sum_{j!=i} relu( U[b,i,p] + V[b,j,p] + c[p] )
//   Wf[q][d] = sum_o W2[q&255][o] * W1[o][(q>=256)*512 + d]   (512x512, bf16)
//   [U|V][r][q] = sum_d x[r][d] * Wf[q][d]                    (one K=512 MFMA GEMM)
//   c[p] = sum_o W2[p][o]*b1[o] + b2[p]
// Two kernels. prep (321 blocks): 64 Wf tiles + cvec + 256 x->bf16 convert
// blocks (uses the CUs that were idle in R4's prep). fused (256 blocks):
// staging is PURE global_load_lds DMA for both Xs and Ws (no VALU, no regs),
// then 32 MFMAs + in-LDS pairwise epilogue.
// Lessons: R5 memset-in-graph 39us; R7 flag-spin +3us; R8 chunk recompute +9us.

typedef unsigned short u16;
typedef __attribute__((ext_vector_type(8))) short short8v;
typedef __attribute__((ext_vector_type(4))) short short4v;
typedef __attribute__((ext_vector_type(4))) float float4v;
typedef __attribute__((ext_vector_type(2))) float float2v;

typedef __attribute__((address_space(1))) const unsigned char* gas_ptr;
typedef __attribute__((address_space(3))) unsigned char* las_ptr;

__device__ __forceinline__ void lds_load16(const void* g, void* l) {
    __builtin_amdgcn_global_load_lds((gas_ptr)g, (las_ptr)l, 16, 0, 0);
}

__device__ __forceinline__ u16 f2bf(float f) {
    unsigned u = __float_as_uint(f);
    return (u16)((u + 0x7fffu + ((u >> 16) & 1u)) >> 16);
}

__device__ __forceinline__ short8v cvt8v(float4v a, float4v b) {
    union { u16 us[8]; short8v v; } o;
    o.us[0] = f2bf(a.x); o.us[1] = f2bf(a.y); o.us[2] = f2bf(a.z); o.us[3] = f2bf(a.w);
    o.us[4] = f2bf(b.x); o.us[5] = f2bf(b.y); o.us[6] = f2bf(b.z); o.us[7] = f2bf(b.w);
    return o.v;
}

// ---------------------------------------------------------------------------
// prep: blocks 0..63   -> Wfb tiles (64q x 64d, K=256 MFMA)
//       block  64      -> cvec
//       blocks 65..320 -> x fp32 -> xb bf16 (256 blocks x 256 thr x 16 elem)
// ---------------------------------------------------------------------------
__global__ __launch_bounds__(256) void prep_kernel(
    const float* __restrict__ x, const float* __restrict__ W1,
    const float* __restrict__ b1, const float* __restrict__ W2,
    const float* __restrict__ b2,
    u16* __restrict__ Wfb, u16* __restrict__ xb, float* __restrict__ cvec) {
    const int bid = blockIdx.x;
    const int t = threadIdx.x;
    if (bid >= 65) {
        int base = (bid - 65) * 4096 + t * 16;
        const float* s = x + base;
        float4v a0 = *(const float4v*)s,        a1 = *(const float4v*)(s + 4);
        float4v a2 = *(const float4v*)(s + 8),  a3 = *(const float4v*)(s + 12);
        *(short8v*)&xb[base]     = cvt8v(a0, a1);
        *(short8v*)&xb[base + 8] = cvt8v(a2, a3);
        return;
    }
    if (bid == 64) {
        float acc = b2[t];
        const float4v* wrow = (const float4v*)(W2 + t * 256);
#pragma unroll 8
        for (int o4 = 0; o4 < 64; ++o4) {
            float4v wv = wrow[o4];
            float4v bv = *(const float4v*)(b1 + o4 * 4);
            acc += wv.x * bv.x + wv.y * bv.y + wv.z * bv.z + wv.w * bv.w;
        }
        cvec[t] = acc;
        return;
    }

    __shared__ __align__(16) u16 As[64 * 264];
    __shared__ __align__(16) u16 Bt[64 * 264];
    const int qt = bid >> 3, dt = bid & 7;
    const int q0 = qt * 64, d0 = dt * 64;
    const int p0 = q0 & 255;
    const int off = (q0 & 256) * 2;          // 0 or 512
    const int lane = t & 63, w = t >> 6;     // 4 waves
    const int rQ = lane >> 4, rM = lane & 15;

    // stage As = W2[p0..p0+63][0:256] -> bf16, 33-unit (264 u16) rows
#pragma unroll
    for (int rr = 0; rr < 8; ++rr) {
        int row = w * 16 + rr * 2 + (lane >> 5);
        int c = lane & 31;
        const float* s = W2 + (p0 + row) * 256 + c * 8;
        float4v a0 = *(const float4v*)s, a1 = *(const float4v*)(s + 4);
        *(short8v*)&As[row * 264 + c * 8] = cvt8v(a0, a1);
    }
    // stage Bt[d][o] = W1[o][off+d0+d] via in-register 4x4 transpose
#pragma unroll
    for (int kk = 0; kk < 4; ++kk) {
        const int m = t & 15, og = t >> 4;
        const int o0 = kk * 64 + og * 4;
        const int d4 = m * 4;
        float4v f0 = *(const float4v*)(W1 + (o0 + 0) * 1024 + off + d0 + d4);
        float4v f1 = *(const float4v*)(W1 + (o0 + 1) * 1024 + off + d0 + d4);
        float4v f2 = *(const float4v*)(W1 + (o0 + 2) * 1024 + off + d0 + d4);
        float4v f3 = *(const float4v*)(W1 + (o0 + 3) * 1024 + off + d0 + d4);
        const int u = o0 >> 3, sub = o0 & 7;
#pragma unroll
        for (int dd = 0; dd < 4; ++dd) {
            int d = d4 + dd;
            int usw = u ^ ((d >> 3) & 7);
            union { u16 us[4]; short4v v; } pk;
            pk.us[0] = f2bf(f0[dd]); pk.us[1] = f2bf(f1[dd]);
            pk.us[2] = f2bf(f2[dd]); pk.us[3] = f2bf(f3[dd]);
            *(short4v*)&Bt[d * 264 + usw * 8 + sub] = pk.v;
        }
    }
    __syncthreads();

    const int wm = w >> 1, wn = w & 1;
    float4v acc[2][2] = {};
#pragma unroll
    for (int ks = 0; ks < 8; ++ks) {
        short8v a[2], bf[2];
#pragma unroll
        for (int mf = 0; mf < 2; ++mf) {
            int row = wm * 32 + mf * 16 + rM;
            a[mf] = *(const short8v*)&As[row * 264 + (ks * 4 + rQ) * 8];
        }
#pragma unroll
        for (int nf = 0; nf < 2; ++nf) {
            int drow = wn * 32 + nf * 16 + rM;
            int ku = (ks * 4 + rQ) ^ ((drow >> 3) & 7);
            bf[nf] = *(const short8v*)&Bt[drow * 264 + ku * 8];
        }
#pragma unroll
        for (int mf = 0; mf < 2; ++mf)
#pragma unroll
            for (int nf = 0; nf < 2; ++nf)
                acc[mf][nf] = __builtin_amdgcn_mfma_f32_16x16x32_bf16(
                    a[mf], bf[nf], acc[mf][nf], 0, 0, 0);
    }

#pragma unroll
    for (int mf = 0; mf < 2; ++mf)
#pragma unroll
        for (int nf = 0; nf < 2; ++nf)
#pragma unroll
            for (int r = 0; r < 4; ++r) {
                int q = q0 + wm * 32 + mf * 16 + rQ * 4 + r;
                int d = d0 + wn * 32 + nf * 16 + rM;
                Wfb[q * 512 + d] = f2bf(acc[mf][nf][r]);
            }
}

// ---------------------------------------------------------------------------
// fused: block (b = bid&31, pc = bid>>5), 512 threads (8 waves).
//   Xs/Ws [64][520 u16]: BOTH staged by pure global_load_lds DMA (row-padded,
//   no VALU, no registers). Then 32 MFMAs/wave (K=512), pairwise epilogue.
// ---------------------------------------------------------------------------
__global__ __launch_bounds__(512, 1) void fused_kernel(
    const u16* __restrict__ xb, const u16* __restrict__ Wfb,
    const float* __restrict__ cvec, float* __restrict__ out) {
    __shared__ __align__(16) u16 smem[2 * 64 * 520];   // 133120 B
    u16* Xs = smem;
    u16* Ws = smem + 64 * 520;
    const int bid = blockIdx.x;
    const int b = bid & 31, pc = bid >> 5;   // same-b blocks share an XCD
    const int p0 = pc * 32;
    const int tid = threadIdx.x;
    const int lane = tid & 63, w = tid >> 6;
    const int rQ = lane >> 4, rM = lane & 15;
    const int uv = w & 1, rh = w >> 1;

    // pure-DMA staging: 16 fire-and-forget loads per wave
#pragma unroll
    for (int rr = 0; rr < 8; ++rr) {
        int row = w * 8 + rr;
        lds_load16(xb + (b * 64 + row) * 512 + lane * 8, (void*)&Xs[row * 520]);
    }
#pragma unroll
    for (int rr = 0; rr < 8; ++rr) {
        int row = w * 8 + rr;
        int q = (row < 32) ? (p0 + row) : (256 + p0 + (row - 32));
        lds_load16(Wfb + q * 512 + lane * 8, (void*)&Ws[row * 520]);
    }
    __syncthreads();   // drains the DMA queue (vmcnt 0)

    float4v acc[2] = {};
#pragma unroll
    for (int ks = 0; ks < 16; ++ks) {
        short8v a = *(const short8v*)&Xs[(rh * 16 + rM) * 520 + (ks * 4 + rQ) * 8];
#pragma unroll
        for (int nf = 0; nf < 2; ++nf) {
            int brow = uv * 32 + nf * 16 + rM;
            short8v bf = *(const short8v*)&Ws[brow * 520 + (ks * 4 + rQ) * 8];
            acc[nf] = __builtin_amdgcn_mfma_f32_16x16x32_bf16(a, bf, acc[nf], 0, 0, 0);
        }
    }
    __syncthreads();   // all LDS reads done; reuse for U/V [64][34] f32

    float* Us = (float*)smem;
    float* Vs = Us + 64 * 34;
    float* dst = uv ? Vs : Us;
#pragma unroll
    for (int nf = 0; nf < 2; ++nf)
#pragma unroll
        for (int r = 0; r < 4; ++r)
            dst[(rh * 16 + rQ * 4 + r) * 34 + nf * 16 + rM] = acc[nf][r];
    __syncthreads();

    // pairwise epilogue on all 512 threads:
    // p2 = tid&15 (2 p via float2), ig = tid>>4 (2 i-rows each)
    const int p2 = tid & 15;
    const int ig = tid >> 4;    // 0..31
    float2v cv = *(const float2v*)(cvec + p0 + p2 * 2);
    float2v u2[2], acc2[2];
#pragma unroll
    for (int ii = 0; ii < 2; ++ii) {
        float2v uu = *(const float2v*)&Us[(ig * 2 + ii) * 34 + p2 * 2];
        u2[ii].x = uu.x + cv.x; u2[ii].y = uu.y + cv.y;
        acc2[ii].x = 0.f; acc2[ii].y = 0.f;
    }
#pragma unroll 8
    for (int j = 0; j < 64; ++j) {
        float2v v = *(const float2v*)&Vs[j * 34 + p2 * 2];
#pragma unroll
        for (int ii = 0; ii < 2; ++ii) {
            acc2[ii].x += fmaxf(u2[ii].x + v.x, 0.f);
            acc2[ii].y += fmaxf(u2[ii].y + v.y, 0.f);
        }
    }
#pragma unroll
    for (int ii = 0; ii < 2; ++ii) {
        int i = ig * 2 + ii;
        float2v vd = *(const float2v*)&Vs[i * 34 + p2 * 2];
        acc2[ii].x -= fmaxf(u2[ii].x + vd.x, 0.f);
        acc2[ii].y -= fmaxf(u2[ii].y + vd.y, 0.f);
        *(float2v*)&out[(b * 64 + i) * 256 + p0 + p2 * 2] = acc2[ii];
    }
}

// ---------------------------------------------------------------------------
extern "C" void kernel_launch(void* const* d_in, const int* in_sizes, int n_in,
                              void* d_out, int out_size, void* d_ws, size_t ws_size,
                              hipStream_t stream) {
    const float* x  = (const float*)d_in[0];   // (32,64,512)
    const float* W1 = (const float*)d_in[1];   // (256,1024)
    const float* b1 = (const float*)d_in[2];   // (256,)
    const float* W2 = (const float*)d_in[3];   // (256,256)
    const float* b2 = (const float*)d_in[4];   // (256,)
    float* out = (float*)d_out;                // (32,64,256)

    // workspace: Wfb (512*512 bf16 = 512KB) | xb (2048*512 bf16 = 2MB) | cvec
    u16* Wfb = (u16*)d_ws;
    u16* xb  = Wfb + 512 * 512;
    float* cvec = (float*)(xb + 2048 * 512);

    prep_kernel<<<321, 256, 0, stream>>>(x, W1, b1, W2, b2, Wfb, xb, cvec);
    fused_kernel<<<256, 512, 0, stream>>>(xb, Wfb, cvec, out);
}